// Round 3
// baseline (1126.338 us; speedup 1.0000x reference)
//
#include <hip/hip_runtime.h>

#define N_NODES 100000
#define N_EDGES 3200000
#define N_GRAPHS 1000
#define NLAYER 4

// ---------------------------------------------------------------------------
// h[v][c] = sum_k x[v][k]*emb_w[k][c] + emb_b[c]
__global__ __launch_bounds__(256) void embed_kernel(
    const float* __restrict__ x, const float* __restrict__ emb_w,
    const float* __restrict__ emb_b, float* __restrict__ h)
{
  int t = blockIdx.x * 256 + threadIdx.x;
  if (t >= N_NODES * 64) return;
  int c = t & 63, v = t >> 6;
  float4 xv = ((const float4*)x)[v];
  float acc = emb_b[c];
  acc = fmaf(xv.x, emb_w[0 * 64 + c], acc);
  acc = fmaf(xv.y, emb_w[1 * 64 + c], acc);
  acc = fmaf(xv.z, emb_w[2 * 64 + c], acc);
  acc = fmaf(xv.w, emb_w[3 * 64 + c], acc);
  h[t] = acc;
}

// ---------------------------------------------------------------------------
// ONE packed u32 atomic per edge: bits 24..31 = count, bits 0..23 = sum(ew*2^16).
// Max degree ~60 (<255), sum < 70*65536 < 2^23 -> no field carry.
// Return value's high byte = this edge's rank within its dst bucket.
__global__ __launch_bounds__(256) void hist_kernel(
    const int* __restrict__ ei, const float* __restrict__ ea,
    unsigned* __restrict__ packed, int* __restrict__ rank)
{
  int e = blockIdx.x * 256 + threadIdx.x;
  if (e >= N_EDGES) return;
  int d = ei[N_EDGES + e];
  unsigned q = (unsigned)(ea[e] * 65536.0f + 0.5f);  // ew in [0,1)
  unsigned old = atomicAdd(&packed[d], (1u << 24) | q);
  rank[e] = (int)(old >> 24);
}

// block-local exclusive scan (256/block) + block sums; input = packed high byte
__global__ __launch_bounds__(256) void scan1_kernel(
    const unsigned* __restrict__ packed,
    int* __restrict__ row_off, int* __restrict__ bsum)
{
  __shared__ int s[256];
  int i = blockIdx.x * 256 + threadIdx.x;
  int x = (i < N_NODES) ? (int)(packed[i] >> 24) : 0;
  s[threadIdx.x] = x;
  __syncthreads();
  for (int off = 1; off < 256; off <<= 1) {
    int y = (threadIdx.x >= off) ? s[threadIdx.x - off] : 0;
    __syncthreads();
    s[threadIdx.x] += y;
    __syncthreads();
  }
  if (i < N_NODES) row_off[i] = s[threadIdx.x] - x;
  if (threadIdx.x == 255) bsum[blockIdx.x] = s[255];
}

__global__ __launch_bounds__(512) void scan2_kernel(
    const int* __restrict__ bsum, int* __restrict__ bpre, int nb)
{
  __shared__ int s[512];
  int x = ((int)threadIdx.x < nb) ? bsum[threadIdx.x] : 0;
  s[threadIdx.x] = x;
  __syncthreads();
  for (int off = 1; off < 512; off <<= 1) {
    int y = (threadIdx.x >= off) ? s[threadIdx.x - off] : 0;
    __syncthreads();
    s[threadIdx.x] += y;
    __syncthreads();
  }
  bpre[threadIdx.x] = s[threadIdx.x] - x;
}

// finalize row_off; also unpack degw from packed low 24 bits
__global__ __launch_bounds__(256) void scan3_kernel(
    int* __restrict__ row_off, const int* __restrict__ bpre,
    const unsigned* __restrict__ packed, float* __restrict__ degw)
{
  int i = blockIdx.x * 256 + threadIdx.x;
  if (i < N_NODES) {
    row_off[i] += bpre[i >> 8];
    degw[i] = (float)(packed[i] & 0xffffffu) * (1.0f / 65536.0f);
  } else if (i == N_NODES) {
    row_off[N_NODES] = N_EDGES;
  }
}

// atomic-free scatter: pos = row_off[dst] + rank[e]; one 8B store per edge
__global__ __launch_bounds__(256) void scatter_kernel(
    const int* __restrict__ ei, const float* __restrict__ ea,
    const int* __restrict__ row_off, const int* __restrict__ rank,
    int2* __restrict__ csr)
{
  int e = blockIdx.x * 256 + threadIdx.x;
  if (e >= N_EDGES) return;
  int d = ei[N_EDGES + e];
  int pos = row_off[d] + rank[e];
  csr[pos] = make_int2(ei[e], __float_as_int(ea[e]));
}

// ---------------------------------------------------------------------------
// fused 3-matvec, 2 nodes per thread:
//   a_out  = h@W1 + b1
//   cc_out = b3 + h@W3 - deg_w * (h@W2)
__device__ __forceinline__ void fma4(float4& a, float s, const float4& w) {
  a.x = fmaf(s, w.x, a.x);
  a.y = fmaf(s, w.y, a.y);
  a.z = fmaf(s, w.z, a.z);
  a.w = fmaf(s, w.w, a.w);
}

__global__ __launch_bounds__(256) void matvec3_kernel(
    const float* __restrict__ h,
    const float* __restrict__ w1, const float* __restrict__ b1,
    const float* __restrict__ w2,
    const float* __restrict__ w3, const float* __restrict__ b3,
    const float* __restrict__ degw,
    float* __restrict__ a_out, float* __restrict__ cc_out)
{
  // LDS: [0..1023]=W2, [1024..2047]=W3, [2048..3071]=W1 (float4 granules)
  __shared__ float4 ws[3 * 1024];
  __shared__ float b1s[64], b3s[64];
  int tid = threadIdx.x;
  const float4* w1v = (const float4*)w1;
  const float4* w2v = (const float4*)w2;
  const float4* w3v = (const float4*)w3;
  for (int i = tid; i < 1024; i += 256) {
    ws[i] = w2v[i];
    ws[1024 + i] = w3v[i];
    ws[2048 + i] = w1v[i];
  }
  if (tid < 64) { b1s[tid] = b1[tid]; b3s[tid] = b3[tid]; }
  __syncthreads();

  int v0 = blockIdx.x * 512 + tid;
  int v1 = v0 + 256;
  bool val0 = v0 < N_NODES, val1 = v1 < N_NODES;
  int v0c = val0 ? v0 : 0;
  int v1c = val1 ? v1 : 0;
  const float4* hp0 = (const float4*)(h + (size_t)v0c * 64);
  const float4* hp1 = (const float4*)(h + (size_t)v1c * 64);
  float dw0 = degw[v0c], dw1 = degw[v1c];
  float4 acc0[16], acc1[16];

  auto mac_loop = [&](const float4* wbase) {
#pragma unroll 2
    for (int k4 = 0; k4 < 16; ++k4) {
      float4 hk0 = hp0[k4];
      float4 hk1 = hp1[k4];
      const float4* wr = wbase + k4 * 64;
#pragma unroll
      for (int j = 0; j < 16; ++j) {
        float4 wa = wr[j], wb = wr[16 + j], wc = wr[32 + j], wd = wr[48 + j];
        fma4(acc0[j], hk0.x, wa); fma4(acc0[j], hk0.y, wb);
        fma4(acc0[j], hk0.z, wc); fma4(acc0[j], hk0.w, wd);
        fma4(acc1[j], hk1.x, wa); fma4(acc1[j], hk1.y, wb);
        fma4(acc1[j], hk1.z, wc); fma4(acc1[j], hk1.w, wd);
      }
    }
  };

  // ---- cc phase: acc = h@W2; acc *= -dw; acc += h@W3; acc += b3 ----
#pragma unroll
  for (int j = 0; j < 16; ++j) {
    acc0[j] = make_float4(0.f, 0.f, 0.f, 0.f);
    acc1[j] = make_float4(0.f, 0.f, 0.f, 0.f);
  }
  mac_loop(&ws[0]);
#pragma unroll
  for (int j = 0; j < 16; ++j) {
    acc0[j].x *= -dw0; acc0[j].y *= -dw0; acc0[j].z *= -dw0; acc0[j].w *= -dw0;
    acc1[j].x *= -dw1; acc1[j].y *= -dw1; acc1[j].z *= -dw1; acc1[j].w *= -dw1;
  }
  mac_loop(&ws[1024]);
  {
    float4* ccp0 = (float4*)(cc_out + (size_t)v0c * 64);
    float4* ccp1 = (float4*)(cc_out + (size_t)v1c * 64);
#pragma unroll
    for (int j = 0; j < 16; ++j) {
      float4 bb = make_float4(b3s[4 * j], b3s[4 * j + 1], b3s[4 * j + 2], b3s[4 * j + 3]);
      if (val0) {
        float4 t = acc0[j];
        t.x += bb.x; t.y += bb.y; t.z += bb.z; t.w += bb.w;
        ccp0[j] = t;
      }
      if (val1) {
        float4 t = acc1[j];
        t.x += bb.x; t.y += bb.y; t.z += bb.z; t.w += bb.w;
        ccp1[j] = t;
      }
    }
  }

  // ---- a phase: acc = b1 + h@W1 ----
#pragma unroll
  for (int j = 0; j < 16; ++j) {
    float4 bb = make_float4(b1s[4 * j], b1s[4 * j + 1], b1s[4 * j + 2], b1s[4 * j + 3]);
    acc0[j] = bb;
    acc1[j] = bb;
  }
  mac_loop(&ws[2048]);
  {
    float4* ap0 = (float4*)(a_out + (size_t)v0c * 64);
    float4* ap1 = (float4*)(a_out + (size_t)v1c * 64);
#pragma unroll
    for (int j = 0; j < 16; ++j) {
      if (val0) ap0[j] = acc0[j];
      if (val1) ap1[j] = acc1[j];
    }
  }
}

// ---------------------------------------------------------------------------
// h_new[v] = relu(cc[v] + sum_{e in CSR(v)} ew_e * a[src_e])
// 4 nodes per wave, 16 lanes (float4) per node: per wave-instruction we serve
// one edge in EACH of the 4 subgroups -> 2.5 issue slots/edge and up to 16
// independent gathers in flight per subgroup (chunked edge-record loads).
__global__ __launch_bounds__(256) void agg_kernel(
    const float4* __restrict__ a4, const float4* __restrict__ cc4,
    const int* __restrict__ row_off, const int2* __restrict__ csr,
    float4* __restrict__ h4)
{
  int wave = (blockIdx.x * 256 + threadIdx.x) >> 6;
  int lane = threadIdx.x & 63;
  int sg = lane >> 4;    // subgroup 0..3
  int li = lane & 15;    // lane within subgroup
  int v = wave * 4 + sg;
  bool valid = v < N_NODES;
  int vc = valid ? v : N_NODES - 1;
  int base = row_off[vc];
  int ecnt = valid ? (row_off[vc + 1] - base) : 0;
  // wave-wide max edge count across the 4 subgroups
  int emax = ecnt;
  emax = max(emax, __shfl_xor(emax, 16));
  emax = max(emax, __shfl_xor(emax, 32));

  float4 acc = valid ? cc4[(size_t)vc * 16 + li] : make_float4(0.f, 0.f, 0.f, 0.f);

  int full = emax & ~15;
  int c0 = 0;
  for (; c0 < full; c0 += 16) {
    int idx = c0 + li;
    int2 er = (idx < ecnt) ? csr[base + idx] : make_int2(0, 0);  // pad: src 0, w 0.0
#pragma unroll
    for (int j = 0; j < 16; ++j) {
      int sl = sg * 16 + j;
      int s = __shfl(er.x, sl);
      float w = __int_as_float(__shfl(er.y, sl));
      float4 av = a4[(size_t)s * 16 + li];
      acc.x = fmaf(w, av.x, acc.x);
      acc.y = fmaf(w, av.y, acc.y);
      acc.z = fmaf(w, av.z, acc.z);
      acc.w = fmaf(w, av.w, acc.w);
    }
  }
  int rem = emax - full;
  if (rem > 0) {
    int idx = c0 + li;
    int2 er = (idx < ecnt) ? csr[base + idx] : make_int2(0, 0);
    for (int j = 0; j < rem; ++j) {  // rem is wave-uniform
      int sl = sg * 16 + j;
      int s = __shfl(er.x, sl);
      float w = __int_as_float(__shfl(er.y, sl));
      float4 av = a4[(size_t)s * 16 + li];
      acc.x = fmaf(w, av.x, acc.x);
      acc.y = fmaf(w, av.y, acc.y);
      acc.z = fmaf(w, av.z, acc.z);
      acc.w = fmaf(w, av.w, acc.w);
    }
  }
  if (valid) {
    acc.x = fmaxf(acc.x, 0.f);
    acc.y = fmaxf(acc.y, 0.f);
    acc.z = fmaxf(acc.z, 0.f);
    acc.w = fmaxf(acc.w, 0.f);
    h4[(size_t)v * 16 + li] = acc;
  }
}

// ---------------------------------------------------------------------------
// fused mean-pool (sorted batch, binary search) + lin1+relu + lin2, wave/graph
__global__ __launch_bounds__(256) void head_kernel(
    const float* __restrict__ h, const int* __restrict__ batch,
    const float* __restrict__ l1w, const float* __restrict__ l1b,
    const float* __restrict__ l2w, const float* __restrict__ l2b,
    float* __restrict__ out)
{
  int g = (blockIdx.x * 256 + threadIdx.x) >> 6;
  int lane = threadIdx.x & 63;
  if (g >= N_GRAPHS) return;
  int lo = 0, hi = N_NODES;
  while (lo < hi) { int mid = (lo + hi) >> 1; if (batch[mid] < g) lo = mid + 1; else hi = mid; }
  int start = lo;
  hi = N_NODES;
  while (lo < hi) { int mid = (lo + hi) >> 1; if (batch[mid] < g + 1) lo = mid + 1; else hi = mid; }
  int end = lo;

  float sum = 0.f;
  for (int v = start; v < end; ++v) sum += h[(size_t)v * 64 + lane];
  float cntf = (float)(end - start);
  float gx = sum / fmaxf(cntf, 1.f);

  float acc = l1b[lane];
  for (int k = 0; k < 64; ++k) {
    float gxk = __shfl(gx, k);
    acc = fmaf(gxk, l1w[k * 64 + lane], acc);
  }
  float t = fmaxf(acc, 0.f);
  float p0 = t * l2w[lane * 3 + 0];
  float p1 = t * l2w[lane * 3 + 1];
  float p2 = t * l2w[lane * 3 + 2];
  for (int off = 32; off > 0; off >>= 1) {
    p0 += __shfl_down(p0, off);
    p1 += __shfl_down(p1, off);
    p2 += __shfl_down(p2, off);
  }
  if (lane == 0) {
    out[g * 3 + 0] = p0 + l2b[0];
    out[g * 3 + 1] = p1 + l2b[1];
    out[g * 3 + 2] = p2 + l2b[2];
  }
}

// ---------------------------------------------------------------------------
extern "C" void kernel_launch(void* const* d_in, const int* in_sizes, int n_in,
                              void* d_out, int out_size, void* d_ws, size_t ws_size,
                              hipStream_t stream)
{
  (void)in_sizes; (void)n_in; (void)out_size; (void)ws_size;
  const float* x     = (const float*)d_in[0];
  const int*   ei    = (const int*)d_in[1];
  const float* ea    = (const float*)d_in[2];
  const int*   batch = (const int*)d_in[3];
  const float* emb_w = (const float*)d_in[4];
  const float* emb_b = (const float*)d_in[5];
  const float* cw1   = (const float*)d_in[6];
  const float* cb1   = (const float*)d_in[7];
  const float* cw2   = (const float*)d_in[8];
  const float* cw3   = (const float*)d_in[9];
  const float* cb3   = (const float*)d_in[10];
  const float* l1w   = (const float*)d_in[11];
  const float* l1b   = (const float*)d_in[12];
  const float* l2w   = (const float*)d_in[13];
  const float* l2b   = (const float*)d_in[14];
  float* out = (float*)d_out;

  char* wsb = (char*)d_ws;
  size_t off = 0;
  auto alloc = [&](size_t bytes) {
    char* p = wsb + off;
    off = (off + bytes + 255) & ~(size_t)255;
    return p;
  };
  float* h       = (float*)alloc(sizeof(float) * (size_t)N_NODES * 64);
  float* a_buf   = (float*)alloc(sizeof(float) * (size_t)N_NODES * 64);
  float* cc_buf  = (float*)alloc(sizeof(float) * (size_t)N_NODES * 64);
  int2*  csr     = (int2*)alloc(sizeof(int2) * (size_t)N_EDGES);
  int*   row_off = (int*)alloc(sizeof(int) * (N_NODES + 1));
  unsigned* packed = (unsigned*)alloc(sizeof(unsigned) * N_NODES);
  float* degw    = (float*)alloc(sizeof(float) * N_NODES);
  int*   bsum    = (int*)alloc(sizeof(int) * 512);
  int*   bpre    = (int*)alloc(sizeof(int) * 512);
  // rank only live between hist and scatter (before matvec writes a_buf)
  int* rank = (int*)a_buf;

  (void)hipMemsetAsync(packed, 0, sizeof(unsigned) * N_NODES, stream);

  embed_kernel<<<(N_NODES * 64 + 255) / 256, 256, 0, stream>>>(x, emb_w, emb_b, h);
  hist_kernel<<<(N_EDGES + 255) / 256, 256, 0, stream>>>(ei, ea, packed, rank);
  int nb = (N_NODES + 255) / 256;  // 391
  scan1_kernel<<<nb, 256, 0, stream>>>(packed, row_off, bsum);
  scan2_kernel<<<1, 512, 0, stream>>>(bsum, bpre, nb);
  scan3_kernel<<<(N_NODES + 1 + 255) / 256, 256, 0, stream>>>(row_off, bpre, packed, degw);
  scatter_kernel<<<(N_EDGES + 255) / 256, 256, 0, stream>>>(ei, ea, row_off, rank, csr);

  int agg_blocks = (N_NODES + 15) / 16;  // 4 nodes/wave, 4 waves/block
  for (int l = 0; l < NLAYER; ++l) {
    matvec3_kernel<<<(N_NODES + 511) / 512, 256, 0, stream>>>(
        h, cw1 + l * 4096, cb1 + l * 64, cw2 + l * 4096, cw3 + l * 4096,
        cb3 + l * 64, degw, a_buf, cc_buf);
    agg_kernel<<<agg_blocks, 256, 0, stream>>>(
        (const float4*)a_buf, (const float4*)cc_buf, row_off, csr, (float4*)h);
  }

  head_kernel<<<(N_GRAPHS * 64 + 255) / 256, 256, 0, stream>>>(
      h, batch, l1w, l1b, l2w, l2b, out);
}

// Round 4
// 891.375 us; speedup vs baseline: 1.2636x; 1.2636x over previous
//
#include <hip/hip_runtime.h>

#define N_NODES 100000
#define N_EDGES 3200000
#define N_GRAPHS 1000
#define NLAYER 4

// round-to-nearest-even f32 -> bf16 (finite inputs)
static __device__ __forceinline__ unsigned f2bf(float f) {
  unsigned u = __float_as_uint(f);
  return (u + 0x7fffu + ((u >> 16) & 1u)) >> 16;
}

// ---------------------------------------------------------------------------
// h[v][c] = sum_k x[v][k]*emb_w[k][c] + emb_b[c]
__global__ __launch_bounds__(256) void embed_kernel(
    const float* __restrict__ x, const float* __restrict__ emb_w,
    const float* __restrict__ emb_b, float* __restrict__ h)
{
  int t = blockIdx.x * 256 + threadIdx.x;
  if (t >= N_NODES * 64) return;
  int c = t & 63, v = t >> 6;
  float4 xv = ((const float4*)x)[v];
  float acc = emb_b[c];
  acc = fmaf(xv.x, emb_w[0 * 64 + c], acc);
  acc = fmaf(xv.y, emb_w[1 * 64 + c], acc);
  acc = fmaf(xv.z, emb_w[2 * 64 + c], acc);
  acc = fmaf(xv.w, emb_w[3 * 64 + c], acc);
  h[t] = acc;
}

// ---------------------------------------------------------------------------
// one u32 count atomic per edge; return value = rank within dst bucket
__global__ __launch_bounds__(256) void hist_kernel(
    const int* __restrict__ ei, unsigned* __restrict__ cnt,
    int* __restrict__ rank)
{
  int e = blockIdx.x * 256 + threadIdx.x;
  if (e >= N_EDGES) return;
  int d = ei[N_EDGES + e];
  rank[e] = (int)atomicAdd(&cnt[d], 1u);
}

// block-local exclusive scan (256/block) + block sums
__global__ __launch_bounds__(256) void scan1_kernel(
    const unsigned* __restrict__ cnt,
    int* __restrict__ row_off, int* __restrict__ bsum)
{
  __shared__ int s[256];
  int i = blockIdx.x * 256 + threadIdx.x;
  int x = (i < N_NODES) ? (int)cnt[i] : 0;
  s[threadIdx.x] = x;
  __syncthreads();
  for (int off = 1; off < 256; off <<= 1) {
    int y = (threadIdx.x >= off) ? s[threadIdx.x - off] : 0;
    __syncthreads();
    s[threadIdx.x] += y;
    __syncthreads();
  }
  if (i < N_NODES) row_off[i] = s[threadIdx.x] - x;
  if (threadIdx.x == 255) bsum[blockIdx.x] = s[255];
}

__global__ __launch_bounds__(512) void scan2_kernel(
    const int* __restrict__ bsum, int* __restrict__ bpre, int nb)
{
  __shared__ int s[512];
  int x = ((int)threadIdx.x < nb) ? bsum[threadIdx.x] : 0;
  s[threadIdx.x] = x;
  __syncthreads();
  for (int off = 1; off < 512; off <<= 1) {
    int y = (threadIdx.x >= off) ? s[threadIdx.x - off] : 0;
    __syncthreads();
    s[threadIdx.x] += y;
    __syncthreads();
  }
  bpre[threadIdx.x] = s[threadIdx.x] - x;
}

__global__ __launch_bounds__(256) void scan3_kernel(
    int* __restrict__ row_off, const int* __restrict__ bpre)
{
  int i = blockIdx.x * 256 + threadIdx.x;
  if (i < N_NODES) {
    row_off[i] += bpre[i >> 8];
  } else if (i == N_NODES) {
    row_off[N_NODES] = N_EDGES;
  }
}

// atomic-free scatter: pos = row_off[dst] + rank[e]; one 8B store per edge
__global__ __launch_bounds__(256) void scatter_kernel(
    const int* __restrict__ ei, const float* __restrict__ ea,
    const int* __restrict__ row_off, const int* __restrict__ rank,
    int2* __restrict__ csr)
{
  int e = blockIdx.x * 256 + threadIdx.x;
  if (e >= N_EDGES) return;
  int d = ei[N_EDGES + e];
  int pos = row_off[d] + rank[e];
  csr[pos] = make_int2(ei[e], __float_as_int(ea[e]));
}

// exact weighted in-degree: degw[v] = sum of ew over CSR row v
__global__ __launch_bounds__(256) void degw_kernel(
    const int* __restrict__ row_off, const int2* __restrict__ csr,
    float* __restrict__ degw)
{
  int v = blockIdx.x * 256 + threadIdx.x;
  if (v >= N_NODES) return;
  int b = row_off[v], e = row_off[v + 1];
  float s = 0.f;
  for (int j = b; j < e; ++j) s += __int_as_float(csr[j].y);
  degw[v] = s;
}

// ---------------------------------------------------------------------------
// fused 3-matvec, 2 nodes per thread:
//   a_out  = bf16(h@W1 + b1)        (gathered operand -> half the bytes)
//   cc_out = b3 + h@W3 - deg_w * (h@W2)   (fp32)
__device__ __forceinline__ void fma4(float4& a, float s, const float4& w) {
  a.x = fmaf(s, w.x, a.x);
  a.y = fmaf(s, w.y, a.y);
  a.z = fmaf(s, w.z, a.z);
  a.w = fmaf(s, w.w, a.w);
}

__global__ __launch_bounds__(256) void matvec3_kernel(
    const float* __restrict__ h,
    const float* __restrict__ w1, const float* __restrict__ b1,
    const float* __restrict__ w2,
    const float* __restrict__ w3, const float* __restrict__ b3,
    const float* __restrict__ degw,
    uint2* __restrict__ a_out, float* __restrict__ cc_out)
{
  // LDS: [0..1023]=W2, [1024..2047]=W3, [2048..3071]=W1 (float4 granules)
  __shared__ float4 ws[3 * 1024];
  __shared__ float b1s[64], b3s[64];
  int tid = threadIdx.x;
  const float4* w1v = (const float4*)w1;
  const float4* w2v = (const float4*)w2;
  const float4* w3v = (const float4*)w3;
  for (int i = tid; i < 1024; i += 256) {
    ws[i] = w2v[i];
    ws[1024 + i] = w3v[i];
    ws[2048 + i] = w1v[i];
  }
  if (tid < 64) { b1s[tid] = b1[tid]; b3s[tid] = b3[tid]; }
  __syncthreads();

  int v0 = blockIdx.x * 512 + tid;
  int v1 = v0 + 256;
  bool val0 = v0 < N_NODES, val1 = v1 < N_NODES;
  int v0c = val0 ? v0 : 0;
  int v1c = val1 ? v1 : 0;
  const float4* hp0 = (const float4*)(h + (size_t)v0c * 64);
  const float4* hp1 = (const float4*)(h + (size_t)v1c * 64);
  float dw0 = degw[v0c], dw1 = degw[v1c];
  float4 acc0[16], acc1[16];

  auto mac_loop = [&](const float4* wbase) {
#pragma unroll 2
    for (int k4 = 0; k4 < 16; ++k4) {
      float4 hk0 = hp0[k4];
      float4 hk1 = hp1[k4];
      const float4* wr = wbase + k4 * 64;
#pragma unroll
      for (int j = 0; j < 16; ++j) {
        float4 wa = wr[j], wb = wr[16 + j], wc = wr[32 + j], wd = wr[48 + j];
        fma4(acc0[j], hk0.x, wa); fma4(acc0[j], hk0.y, wb);
        fma4(acc0[j], hk0.z, wc); fma4(acc0[j], hk0.w, wd);
        fma4(acc1[j], hk1.x, wa); fma4(acc1[j], hk1.y, wb);
        fma4(acc1[j], hk1.z, wc); fma4(acc1[j], hk1.w, wd);
      }
    }
  };

  // ---- cc phase: acc = h@W2; acc *= -dw; acc += h@W3; acc += b3 ----
#pragma unroll
  for (int j = 0; j < 16; ++j) {
    acc0[j] = make_float4(0.f, 0.f, 0.f, 0.f);
    acc1[j] = make_float4(0.f, 0.f, 0.f, 0.f);
  }
  mac_loop(&ws[0]);
#pragma unroll
  for (int j = 0; j < 16; ++j) {
    acc0[j].x *= -dw0; acc0[j].y *= -dw0; acc0[j].z *= -dw0; acc0[j].w *= -dw0;
    acc1[j].x *= -dw1; acc1[j].y *= -dw1; acc1[j].z *= -dw1; acc1[j].w *= -dw1;
  }
  mac_loop(&ws[1024]);
  {
    float4* ccp0 = (float4*)(cc_out + (size_t)v0c * 64);
    float4* ccp1 = (float4*)(cc_out + (size_t)v1c * 64);
#pragma unroll
    for (int j = 0; j < 16; ++j) {
      float4 bb = make_float4(b3s[4 * j], b3s[4 * j + 1], b3s[4 * j + 2], b3s[4 * j + 3]);
      if (val0) {
        float4 t = acc0[j];
        t.x += bb.x; t.y += bb.y; t.z += bb.z; t.w += bb.w;
        ccp0[j] = t;
      }
      if (val1) {
        float4 t = acc1[j];
        t.x += bb.x; t.y += bb.y; t.z += bb.z; t.w += bb.w;
        ccp1[j] = t;
      }
    }
  }

  // ---- a phase: acc = b1 + h@W1, stored as bf16 ----
#pragma unroll
  for (int j = 0; j < 16; ++j) {
    float4 bb = make_float4(b1s[4 * j], b1s[4 * j + 1], b1s[4 * j + 2], b1s[4 * j + 3]);
    acc0[j] = bb;
    acc1[j] = bb;
  }
  mac_loop(&ws[2048]);
  {
    uint2* ap0 = a_out + (size_t)v0c * 16;
    uint2* ap1 = a_out + (size_t)v1c * 16;
#pragma unroll
    for (int j = 0; j < 16; ++j) {
      if (val0) {
        float4 t = acc0[j];
        uint2 p;
        p.x = f2bf(t.x) | (f2bf(t.y) << 16);
        p.y = f2bf(t.z) | (f2bf(t.w) << 16);
        ap0[j] = p;
      }
      if (val1) {
        float4 t = acc1[j];
        uint2 p;
        p.x = f2bf(t.x) | (f2bf(t.y) << 16);
        p.y = f2bf(t.z) | (f2bf(t.w) << 16);
        ap1[j] = p;
      }
    }
  }
}

// ---------------------------------------------------------------------------
// h_new[v] = relu(cc[v] + sum_{e in CSR(v)} ew_e * a[src_e])
// 4 nodes/wave, 16 lanes per node; a-rows are bf16 (128 B) -> half gather bytes.
__global__ __launch_bounds__(256) void agg_kernel(
    const uint2* __restrict__ a2, const float4* __restrict__ cc4,
    const int* __restrict__ row_off, const int2* __restrict__ csr,
    float4* __restrict__ h4)
{
  int wave = (blockIdx.x * 256 + threadIdx.x) >> 6;
  int lane = threadIdx.x & 63;
  int sg = lane >> 4;    // subgroup 0..3
  int li = lane & 15;    // lane within subgroup (channels 4li..4li+3)
  int v = wave * 4 + sg;
  bool valid = v < N_NODES;
  int vc = valid ? v : N_NODES - 1;
  int base = row_off[vc];
  int ecnt = valid ? (row_off[vc + 1] - base) : 0;
  int emax = ecnt;
  emax = max(emax, __shfl_xor(emax, 16));
  emax = max(emax, __shfl_xor(emax, 32));

  float4 acc = valid ? cc4[(size_t)vc * 16 + li] : make_float4(0.f, 0.f, 0.f, 0.f);

  int full = emax & ~15;
  int c0 = 0;
  for (; c0 < full; c0 += 16) {
    int idx = c0 + li;
    int2 er = (idx < ecnt) ? csr[base + idx] : make_int2(0, 0);  // pad: src 0, w 0.0
#pragma unroll
    for (int j = 0; j < 16; ++j) {
      int sl = sg * 16 + j;
      int s = __shfl(er.x, sl);
      float w = __int_as_float(__shfl(er.y, sl));
      uint2 u = a2[(size_t)s * 16 + li];
      acc.x = fmaf(w, __uint_as_float(u.x << 16), acc.x);
      acc.y = fmaf(w, __uint_as_float(u.x & 0xffff0000u), acc.y);
      acc.z = fmaf(w, __uint_as_float(u.y << 16), acc.z);
      acc.w = fmaf(w, __uint_as_float(u.y & 0xffff0000u), acc.w);
    }
  }
  int rem = emax - full;
  if (rem > 0) {
    int idx = c0 + li;
    int2 er = (idx < ecnt) ? csr[base + idx] : make_int2(0, 0);
    for (int j = 0; j < rem; ++j) {  // rem is wave-uniform
      int sl = sg * 16 + j;
      int s = __shfl(er.x, sl);
      float w = __int_as_float(__shfl(er.y, sl));
      uint2 u = a2[(size_t)s * 16 + li];
      acc.x = fmaf(w, __uint_as_float(u.x << 16), acc.x);
      acc.y = fmaf(w, __uint_as_float(u.x & 0xffff0000u), acc.y);
      acc.z = fmaf(w, __uint_as_float(u.y << 16), acc.z);
      acc.w = fmaf(w, __uint_as_float(u.y & 0xffff0000u), acc.w);
    }
  }
  if (valid) {
    acc.x = fmaxf(acc.x, 0.f);
    acc.y = fmaxf(acc.y, 0.f);
    acc.z = fmaxf(acc.z, 0.f);
    acc.w = fmaxf(acc.w, 0.f);
    h4[(size_t)v * 16 + li] = acc;
  }
}

// ---------------------------------------------------------------------------
// fused mean-pool (sorted batch, binary search) + lin1+relu + lin2, wave/graph
__global__ __launch_bounds__(256) void head_kernel(
    const float* __restrict__ h, const int* __restrict__ batch,
    const float* __restrict__ l1w, const float* __restrict__ l1b,
    const float* __restrict__ l2w, const float* __restrict__ l2b,
    float* __restrict__ out)
{
  int g = (blockIdx.x * 256 + threadIdx.x) >> 6;
  int lane = threadIdx.x & 63;
  if (g >= N_GRAPHS) return;
  int lo = 0, hi = N_NODES;
  while (lo < hi) { int mid = (lo + hi) >> 1; if (batch[mid] < g) lo = mid + 1; else hi = mid; }
  int start = lo;
  hi = N_NODES;
  while (lo < hi) { int mid = (lo + hi) >> 1; if (batch[mid] < g + 1) lo = mid + 1; else hi = mid; }
  int end = lo;

  float sum = 0.f;
  for (int v = start; v < end; ++v) sum += h[(size_t)v * 64 + lane];
  float cntf = (float)(end - start);
  float gx = sum / fmaxf(cntf, 1.f);

  float acc = l1b[lane];
  for (int k = 0; k < 64; ++k) {
    float gxk = __shfl(gx, k);
    acc = fmaf(gxk, l1w[k * 64 + lane], acc);
  }
  float t = fmaxf(acc, 0.f);
  float p0 = t * l2w[lane * 3 + 0];
  float p1 = t * l2w[lane * 3 + 1];
  float p2 = t * l2w[lane * 3 + 2];
  for (int off = 32; off > 0; off >>= 1) {
    p0 += __shfl_down(p0, off);
    p1 += __shfl_down(p1, off);
    p2 += __shfl_down(p2, off);
  }
  if (lane == 0) {
    out[g * 3 + 0] = p0 + l2b[0];
    out[g * 3 + 1] = p1 + l2b[1];
    out[g * 3 + 2] = p2 + l2b[2];
  }
}

// ---------------------------------------------------------------------------
extern "C" void kernel_launch(void* const* d_in, const int* in_sizes, int n_in,
                              void* d_out, int out_size, void* d_ws, size_t ws_size,
                              hipStream_t stream)
{
  (void)in_sizes; (void)n_in; (void)out_size; (void)ws_size;
  const float* x     = (const float*)d_in[0];
  const int*   ei    = (const int*)d_in[1];
  const float* ea    = (const float*)d_in[2];
  const int*   batch = (const int*)d_in[3];
  const float* emb_w = (const float*)d_in[4];
  const float* emb_b = (const float*)d_in[5];
  const float* cw1   = (const float*)d_in[6];
  const float* cb1   = (const float*)d_in[7];
  const float* cw2   = (const float*)d_in[8];
  const float* cw3   = (const float*)d_in[9];
  const float* cb3   = (const float*)d_in[10];
  const float* l1w   = (const float*)d_in[11];
  const float* l1b   = (const float*)d_in[12];
  const float* l2w   = (const float*)d_in[13];
  const float* l2b   = (const float*)d_in[14];
  float* out = (float*)d_out;

  char* wsb = (char*)d_ws;
  size_t off = 0;
  auto alloc = [&](size_t bytes) {
    char* p = wsb + off;
    off = (off + bytes + 255) & ~(size_t)255;
    return p;
  };
  float* h       = (float*)alloc(sizeof(float) * (size_t)N_NODES * 64);
  uint2* a_bf    = (uint2*)alloc(sizeof(uint2) * (size_t)N_NODES * 16);   // bf16 rows
  float* cc_buf  = (float*)alloc(sizeof(float) * (size_t)N_NODES * 64);
  int2*  csr     = (int2*)alloc(sizeof(int2) * (size_t)N_EDGES);
  int*   row_off = (int*)alloc(sizeof(int) * (N_NODES + 1));
  unsigned* cnt  = (unsigned*)alloc(sizeof(unsigned) * N_NODES);
  float* degw    = (float*)alloc(sizeof(float) * N_NODES);
  int*   bsum    = (int*)alloc(sizeof(int) * 512);
  int*   bpre    = (int*)alloc(sizeof(int) * 512);
  // rank only live between hist and scatter (before matvec writes cc_buf)
  int* rank = (int*)cc_buf;

  (void)hipMemsetAsync(cnt, 0, sizeof(unsigned) * N_NODES, stream);

  embed_kernel<<<(N_NODES * 64 + 255) / 256, 256, 0, stream>>>(x, emb_w, emb_b, h);
  hist_kernel<<<(N_EDGES + 255) / 256, 256, 0, stream>>>(ei, cnt, rank);
  int nb = (N_NODES + 255) / 256;  // 391
  scan1_kernel<<<nb, 256, 0, stream>>>(cnt, row_off, bsum);
  scan2_kernel<<<1, 512, 0, stream>>>(bsum, bpre, nb);
  scan3_kernel<<<(N_NODES + 1 + 255) / 256, 256, 0, stream>>>(row_off, bpre);
  scatter_kernel<<<(N_EDGES + 255) / 256, 256, 0, stream>>>(ei, ea, row_off, rank, csr);
  degw_kernel<<<nb, 256, 0, stream>>>(row_off, csr, degw);

  int agg_blocks = (N_NODES + 15) / 16;  // 4 nodes/wave, 4 waves/block
  for (int l = 0; l < NLAYER; ++l) {
    matvec3_kernel<<<(N_NODES + 511) / 512, 256, 0, stream>>>(
        h, cw1 + l * 4096, cb1 + l * 64, cw2 + l * 4096, cw3 + l * 4096,
        cb3 + l * 64, degw, a_bf, cc_buf);
    agg_kernel<<<agg_blocks, 256, 0, stream>>>(
        a_bf, (const float4*)cc_buf, row_off, csr, (float4*)h);
  }

  head_kernel<<<(N_GRAPHS * 64 + 255) / 256, 256, 0, stream>>>(
      h, batch, l1w, l1b, l2w, l2b, out);
}

// Round 5
// 800.825 us; speedup vs baseline: 1.4065x; 1.1131x over previous
//
#include <hip/hip_runtime.h>

#define N_NODES 100000
#define N_EDGES 3200000
#define N_GRAPHS 1000
#define NLAYER 4
#define NB 391           // coarse buckets: dst>>8, 391*256 = 100096 >= N_NODES
#define G1 782           // edge-pass blocks: 782*4096 >= N_EDGES
#define EPB 4096         // edges per block in edge passes

// round-to-nearest-even f32 -> bf16 (finite inputs)
static __device__ __forceinline__ unsigned f2bf(float f) {
  unsigned u = __float_as_uint(f);
  return (u + 0x7fffu + ((u >> 16) & 1u)) >> 16;
}

// ---------------------------------------------------------------------------
// h[v][c] = sum_k x[v][k]*emb_w[k][c] + emb_b[c]
__global__ __launch_bounds__(256) void embed_kernel(
    const float* __restrict__ x, const float* __restrict__ emb_w,
    const float* __restrict__ emb_b, float* __restrict__ h)
{
  int t = blockIdx.x * 256 + threadIdx.x;
  if (t >= N_NODES * 64) return;
  int c = t & 63, v = t >> 6;
  float4 xv = ((const float4*)x)[v];
  float acc = emb_b[c];
  acc = fmaf(xv.x, emb_w[0 * 64 + c], acc);
  acc = fmaf(xv.y, emb_w[1 * 64 + c], acc);
  acc = fmaf(xv.z, emb_w[2 * 64 + c], acc);
  acc = fmaf(xv.w, emb_w[3 * 64 + c], acc);
  h[t] = acc;
}

// ---------------------------------------------------------------------------
// A: per-block LDS histogram of coarse bucket (dst>>8). No device atomics.
__global__ __launch_bounds__(256) void bhist_kernel(
    const int* __restrict__ ei, int* __restrict__ bhist)
{
  __shared__ unsigned hist[NB];
  for (int i = threadIdx.x; i < NB; i += 256) hist[i] = 0;
  __syncthreads();
  int base = blockIdx.x * EPB;
#pragma unroll
  for (int i = 0; i < 16; ++i) {
    int e = base + i * 256 + threadIdx.x;
    if (e < N_EDGES) atomicAdd(&hist[((unsigned)ei[N_EDGES + e]) >> 8], 1u);
  }
  __syncthreads();
  for (int i = threadIdx.x; i < NB; i += 256)
    bhist[blockIdx.x * NB + i] = (int)hist[i];
}

// B1: per-bucket column exclusive scan over the G1 block rows (in place);
// column total -> tots[b]
__global__ __launch_bounds__(256) void colscan_kernel(
    int* __restrict__ bhist, int* __restrict__ tots)
{
  int b = blockIdx.x;  // bucket
  __shared__ int s[256];
  __shared__ int carry;
  if (threadIdx.x == 0) carry = 0;
  __syncthreads();
  for (int c0 = 0; c0 < G1; c0 += 256) {
    int g = c0 + threadIdx.x;
    int v = (g < G1) ? bhist[g * NB + b] : 0;
    s[threadIdx.x] = v;
    __syncthreads();
    for (int off = 1; off < 256; off <<= 1) {
      int y = (threadIdx.x >= off) ? s[threadIdx.x - off] : 0;
      __syncthreads();
      s[threadIdx.x] += y;
      __syncthreads();
    }
    if (g < G1) bhist[g * NB + b] = carry + s[threadIdx.x] - v;  // exclusive
    __syncthreads();
    if (threadIdx.x == 0) carry += s[255];
    __syncthreads();
  }
  if (threadIdx.x == 0) tots[b] = carry;
}

// B2: exclusive scan of bucket totals -> bucket base offsets bb[0..NB]
__global__ __launch_bounds__(512) void bucketscan_kernel(
    const int* __restrict__ tots, int* __restrict__ bb)
{
  __shared__ int s[512];
  int x = ((int)threadIdx.x < NB) ? tots[threadIdx.x] : 0;
  s[threadIdx.x] = x;
  __syncthreads();
  for (int off = 1; off < 512; off <<= 1) {
    int y = (threadIdx.x >= off) ? s[threadIdx.x - off] : 0;
    __syncthreads();
    s[threadIdx.x] += y;
    __syncthreads();
  }
  if ((int)threadIdx.x < NB) bb[threadIdx.x] = s[threadIdx.x] - x;
  if (threadIdx.x == 0) bb[NB] = N_EDGES;
}

// C: scatter edges into coarse buckets. LDS cursors only (no device atomics).
// record: x = src | ((dst&255)<<17)   (src < 2^17), y = ew bits (exact f32)
__global__ __launch_bounds__(256) void bscatter_kernel(
    const int* __restrict__ ei, const float* __restrict__ ea,
    const int* __restrict__ bhist, const int* __restrict__ bb,
    int2* __restrict__ tmp)
{
  __shared__ unsigned cur[NB];
  for (int i = threadIdx.x; i < NB; i += 256)
    cur[i] = (unsigned)(bb[i] + bhist[blockIdx.x * NB + i]);
  __syncthreads();
  int base = blockIdx.x * EPB;
#pragma unroll
  for (int i = 0; i < 16; ++i) {
    int e = base + i * 256 + threadIdx.x;
    if (e < N_EDGES) {
      int d = ei[N_EDGES + e];
      int srcv = ei[e];
      float w = ea[e];
      unsigned pos = atomicAdd(&cur[((unsigned)d) >> 8], 1u);
      tmp[pos] = make_int2(srcv | ((d & 255) << 17), __float_as_int(w));
    }
  }
}

// D: one block per bucket: 256-bin LDS counting sort within bucket ->
// final dst-sorted csr (coalesced window), plus row_off and degw for free.
__global__ __launch_bounds__(256) void bucket_sort_kernel(
    const int* __restrict__ bb, const int2* __restrict__ tmp,
    int2* __restrict__ csr, int* __restrict__ row_off, float* __restrict__ degw)
{
  int j = blockIdx.x;
  int b0 = bb[j], b1 = bb[j + 1];
  int nE = b1 - b0;
  __shared__ unsigned hist[256];
  __shared__ float dws[256];
  __shared__ int scanbuf[256];
  __shared__ unsigned cur[256];
  int t = threadIdx.x;
  hist[t] = 0;
  dws[t] = 0.f;
  __syncthreads();
  for (int i = t; i < nE; i += 256) {
    int2 r = tmp[b0 + i];
    int bin = ((unsigned)r.x) >> 17;
    atomicAdd(&hist[bin], 1u);
    atomicAdd(&dws[bin], __int_as_float(r.y));
  }
  __syncthreads();
  int v = (int)hist[t];
  scanbuf[t] = v;
  __syncthreads();
  for (int off = 1; off < 256; off <<= 1) {
    int y = (t >= off) ? scanbuf[t - off] : 0;
    __syncthreads();
    scanbuf[t] += y;
    __syncthreads();
  }
  int myexcl = scanbuf[t] - v;
  cur[t] = (unsigned)myexcl;
  int vnode = (j << 8) + t;
  if (vnode < N_NODES) {
    row_off[vnode] = b0 + myexcl;
    degw[vnode] = dws[t];
  }
  if (j == NB - 1 && t == 0) row_off[N_NODES] = N_EDGES;
  __syncthreads();
  for (int i = t; i < nE; i += 256) {
    int2 r = tmp[b0 + i];
    int bin = ((unsigned)r.x) >> 17;
    unsigned p = atomicAdd(&cur[bin], 1u);
    csr[b0 + (int)p] = make_int2(r.x & 0x1FFFF, r.y);
  }
}

// ---------------------------------------------------------------------------
// fused 3-matvec, 2 nodes per thread:
//   a_out  = bf16(h@W1 + b1)
//   cc_out = b3 + h@W3 - deg_w * (h@W2)   (fp32)
__device__ __forceinline__ void fma4(float4& a, float s, const float4& w) {
  a.x = fmaf(s, w.x, a.x);
  a.y = fmaf(s, w.y, a.y);
  a.z = fmaf(s, w.z, a.z);
  a.w = fmaf(s, w.w, a.w);
}

__global__ __launch_bounds__(256) void matvec3_kernel(
    const float* __restrict__ h,
    const float* __restrict__ w1, const float* __restrict__ b1,
    const float* __restrict__ w2,
    const float* __restrict__ w3, const float* __restrict__ b3,
    const float* __restrict__ degw,
    uint2* __restrict__ a_out, float* __restrict__ cc_out)
{
  __shared__ float4 ws[3 * 1024];
  __shared__ float b1s[64], b3s[64];
  int tid = threadIdx.x;
  const float4* w1v = (const float4*)w1;
  const float4* w2v = (const float4*)w2;
  const float4* w3v = (const float4*)w3;
  for (int i = tid; i < 1024; i += 256) {
    ws[i] = w2v[i];
    ws[1024 + i] = w3v[i];
    ws[2048 + i] = w1v[i];
  }
  if (tid < 64) { b1s[tid] = b1[tid]; b3s[tid] = b3[tid]; }
  __syncthreads();

  int v0 = blockIdx.x * 512 + tid;
  int v1 = v0 + 256;
  bool val0 = v0 < N_NODES, val1 = v1 < N_NODES;
  int v0c = val0 ? v0 : 0;
  int v1c = val1 ? v1 : 0;
  const float4* hp0 = (const float4*)(h + (size_t)v0c * 64);
  const float4* hp1 = (const float4*)(h + (size_t)v1c * 64);
  float dw0 = degw[v0c], dw1 = degw[v1c];
  float4 acc0[16], acc1[16];

  auto mac_loop = [&](const float4* wbase) {
#pragma unroll 2
    for (int k4 = 0; k4 < 16; ++k4) {
      float4 hk0 = hp0[k4];
      float4 hk1 = hp1[k4];
      const float4* wr = wbase + k4 * 64;
#pragma unroll
      for (int j = 0; j < 16; ++j) {
        float4 wa = wr[j], wb = wr[16 + j], wc = wr[32 + j], wd = wr[48 + j];
        fma4(acc0[j], hk0.x, wa); fma4(acc0[j], hk0.y, wb);
        fma4(acc0[j], hk0.z, wc); fma4(acc0[j], hk0.w, wd);
        fma4(acc1[j], hk1.x, wa); fma4(acc1[j], hk1.y, wb);
        fma4(acc1[j], hk1.z, wc); fma4(acc1[j], hk1.w, wd);
      }
    }
  };

  // ---- cc phase ----
#pragma unroll
  for (int j = 0; j < 16; ++j) {
    acc0[j] = make_float4(0.f, 0.f, 0.f, 0.f);
    acc1[j] = make_float4(0.f, 0.f, 0.f, 0.f);
  }
  mac_loop(&ws[0]);
#pragma unroll
  for (int j = 0; j < 16; ++j) {
    acc0[j].x *= -dw0; acc0[j].y *= -dw0; acc0[j].z *= -dw0; acc0[j].w *= -dw0;
    acc1[j].x *= -dw1; acc1[j].y *= -dw1; acc1[j].z *= -dw1; acc1[j].w *= -dw1;
  }
  mac_loop(&ws[1024]);
  {
    float4* ccp0 = (float4*)(cc_out + (size_t)v0c * 64);
    float4* ccp1 = (float4*)(cc_out + (size_t)v1c * 64);
#pragma unroll
    for (int j = 0; j < 16; ++j) {
      float4 bb3 = make_float4(b3s[4 * j], b3s[4 * j + 1], b3s[4 * j + 2], b3s[4 * j + 3]);
      if (val0) {
        float4 t = acc0[j];
        t.x += bb3.x; t.y += bb3.y; t.z += bb3.z; t.w += bb3.w;
        ccp0[j] = t;
      }
      if (val1) {
        float4 t = acc1[j];
        t.x += bb3.x; t.y += bb3.y; t.z += bb3.z; t.w += bb3.w;
        ccp1[j] = t;
      }
    }
  }

  // ---- a phase (bf16 out) ----
#pragma unroll
  for (int j = 0; j < 16; ++j) {
    float4 bb1 = make_float4(b1s[4 * j], b1s[4 * j + 1], b1s[4 * j + 2], b1s[4 * j + 3]);
    acc0[j] = bb1;
    acc1[j] = bb1;
  }
  mac_loop(&ws[2048]);
  {
    uint2* ap0 = a_out + (size_t)v0c * 16;
    uint2* ap1 = a_out + (size_t)v1c * 16;
#pragma unroll
    for (int j = 0; j < 16; ++j) {
      if (val0) {
        float4 t = acc0[j];
        uint2 p;
        p.x = f2bf(t.x) | (f2bf(t.y) << 16);
        p.y = f2bf(t.z) | (f2bf(t.w) << 16);
        ap0[j] = p;
      }
      if (val1) {
        float4 t = acc1[j];
        uint2 p;
        p.x = f2bf(t.x) | (f2bf(t.y) << 16);
        p.y = f2bf(t.z) | (f2bf(t.w) << 16);
        ap1[j] = p;
      }
    }
  }
}

// ---------------------------------------------------------------------------
// h_new[v] = relu(cc[v] + sum_{e in CSR(v)} ew_e * a[src_e])
// 4 nodes/wave, 16 lanes per node; a-rows bf16 (128 B).
__global__ __launch_bounds__(256) void agg_kernel(
    const uint2* __restrict__ a2, const float4* __restrict__ cc4,
    const int* __restrict__ row_off, const int2* __restrict__ csr,
    float4* __restrict__ h4)
{
  int wave = (blockIdx.x * 256 + threadIdx.x) >> 6;
  int lane = threadIdx.x & 63;
  int sg = lane >> 4;
  int li = lane & 15;
  int v = wave * 4 + sg;
  bool valid = v < N_NODES;
  int vc = valid ? v : N_NODES - 1;
  int base = row_off[vc];
  int ecnt = valid ? (row_off[vc + 1] - base) : 0;
  int emax = ecnt;
  emax = max(emax, __shfl_xor(emax, 16));
  emax = max(emax, __shfl_xor(emax, 32));

  float4 acc = valid ? cc4[(size_t)vc * 16 + li] : make_float4(0.f, 0.f, 0.f, 0.f);

  int full = emax & ~15;
  int c0 = 0;
  for (; c0 < full; c0 += 16) {
    int idx = c0 + li;
    int2 er = (idx < ecnt) ? csr[base + idx] : make_int2(0, 0);
#pragma unroll
    for (int j = 0; j < 16; ++j) {
      int sl = sg * 16 + j;
      int s = __shfl(er.x, sl);
      float w = __int_as_float(__shfl(er.y, sl));
      uint2 u = a2[(size_t)s * 16 + li];
      acc.x = fmaf(w, __uint_as_float(u.x << 16), acc.x);
      acc.y = fmaf(w, __uint_as_float(u.x & 0xffff0000u), acc.y);
      acc.z = fmaf(w, __uint_as_float(u.y << 16), acc.z);
      acc.w = fmaf(w, __uint_as_float(u.y & 0xffff0000u), acc.w);
    }
  }
  int rem = emax - full;
  if (rem > 0) {
    int idx = c0 + li;
    int2 er = (idx < ecnt) ? csr[base + idx] : make_int2(0, 0);
    for (int j = 0; j < rem; ++j) {
      int sl = sg * 16 + j;
      int s = __shfl(er.x, sl);
      float w = __int_as_float(__shfl(er.y, sl));
      uint2 u = a2[(size_t)s * 16 + li];
      acc.x = fmaf(w, __uint_as_float(u.x << 16), acc.x);
      acc.y = fmaf(w, __uint_as_float(u.x & 0xffff0000u), acc.y);
      acc.z = fmaf(w, __uint_as_float(u.y << 16), acc.z);
      acc.w = fmaf(w, __uint_as_float(u.y & 0xffff0000u), acc.w);
    }
  }
  if (valid) {
    acc.x = fmaxf(acc.x, 0.f);
    acc.y = fmaxf(acc.y, 0.f);
    acc.z = fmaxf(acc.z, 0.f);
    acc.w = fmaxf(acc.w, 0.f);
    h4[(size_t)v * 16 + li] = acc;
  }
}

// ---------------------------------------------------------------------------
// fused mean-pool (sorted batch, binary search) + lin1+relu + lin2, wave/graph
__global__ __launch_bounds__(256) void head_kernel(
    const float* __restrict__ h, const int* __restrict__ batch,
    const float* __restrict__ l1w, const float* __restrict__ l1b,
    const float* __restrict__ l2w, const float* __restrict__ l2b,
    float* __restrict__ out)
{
  int g = (blockIdx.x * 256 + threadIdx.x) >> 6;
  int lane = threadIdx.x & 63;
  if (g >= N_GRAPHS) return;
  int lo = 0, hi = N_NODES;
  while (lo < hi) { int mid = (lo + hi) >> 1; if (batch[mid] < g) lo = mid + 1; else hi = mid; }
  int start = lo;
  hi = N_NODES;
  while (lo < hi) { int mid = (lo + hi) >> 1; if (batch[mid] < g + 1) lo = mid + 1; else hi = mid; }
  int end = lo;

  float sum = 0.f;
  for (int v = start; v < end; ++v) sum += h[(size_t)v * 64 + lane];
  float cntf = (float)(end - start);
  float gx = sum / fmaxf(cntf, 1.f);

  float acc = l1b[lane];
  for (int k = 0; k < 64; ++k) {
    float gxk = __shfl(gx, k);
    acc = fmaf(gxk, l1w[k * 64 + lane], acc);
  }
  float t = fmaxf(acc, 0.f);
  float p0 = t * l2w[lane * 3 + 0];
  float p1 = t * l2w[lane * 3 + 1];
  float p2 = t * l2w[lane * 3 + 2];
  for (int off = 32; off > 0; off >>= 1) {
    p0 += __shfl_down(p0, off);
    p1 += __shfl_down(p1, off);
    p2 += __shfl_down(p2, off);
  }
  if (lane == 0) {
    out[g * 3 + 0] = p0 + l2b[0];
    out[g * 3 + 1] = p1 + l2b[1];
    out[g * 3 + 2] = p2 + l2b[2];
  }
}

// ---------------------------------------------------------------------------
extern "C" void kernel_launch(void* const* d_in, const int* in_sizes, int n_in,
                              void* d_out, int out_size, void* d_ws, size_t ws_size,
                              hipStream_t stream)
{
  (void)in_sizes; (void)n_in; (void)out_size; (void)ws_size;
  const float* x     = (const float*)d_in[0];
  const int*   ei    = (const int*)d_in[1];
  const float* ea    = (const float*)d_in[2];
  const int*   batch = (const int*)d_in[3];
  const float* emb_w = (const float*)d_in[4];
  const float* emb_b = (const float*)d_in[5];
  const float* cw1   = (const float*)d_in[6];
  const float* cb1   = (const float*)d_in[7];
  const float* cw2   = (const float*)d_in[8];
  const float* cw3   = (const float*)d_in[9];
  const float* cb3   = (const float*)d_in[10];
  const float* l1w   = (const float*)d_in[11];
  const float* l1b   = (const float*)d_in[12];
  const float* l2w   = (const float*)d_in[13];
  const float* l2b   = (const float*)d_in[14];
  float* out = (float*)d_out;

  char* wsb = (char*)d_ws;
  size_t off = 0;
  auto alloc = [&](size_t bytes) {
    char* p = wsb + off;
    off = (off + bytes + 255) & ~(size_t)255;
    return p;
  };
  float* h       = (float*)alloc(sizeof(float) * (size_t)N_NODES * 64);
  uint2* a_bf    = (uint2*)alloc(sizeof(uint2) * (size_t)N_NODES * 16);
  float* cc_buf  = (float*)alloc(sizeof(float) * (size_t)N_NODES * 64);
  int2*  csr     = (int2*)alloc(sizeof(int2) * (size_t)N_EDGES);
  int*   row_off = (int*)alloc(sizeof(int) * (N_NODES + 1));
  float* degw    = (float*)alloc(sizeof(float) * N_NODES);
  int*   bhist   = (int*)alloc(sizeof(int) * (size_t)G1 * NB);
  int*   tots    = (int*)alloc(sizeof(int) * NB);
  int*   bb      = (int*)alloc(sizeof(int) * (NB + 1));
  // tmp bucket records alias cc_buf: tmp is dead before matvec first writes cc.
  int2* tmp = (int2*)cc_buf;

  embed_kernel<<<(N_NODES * 64 + 255) / 256, 256, 0, stream>>>(x, emb_w, emb_b, h);
  bhist_kernel<<<G1, 256, 0, stream>>>(ei, bhist);
  colscan_kernel<<<NB, 256, 0, stream>>>(bhist, tots);
  bucketscan_kernel<<<1, 512, 0, stream>>>(tots, bb);
  bscatter_kernel<<<G1, 256, 0, stream>>>(ei, ea, bhist, bb, tmp);
  bucket_sort_kernel<<<NB, 256, 0, stream>>>(bb, tmp, csr, row_off, degw);

  int agg_blocks = (N_NODES + 15) / 16;
  for (int l = 0; l < NLAYER; ++l) {
    matvec3_kernel<<<(N_NODES + 511) / 512, 256, 0, stream>>>(
        h, cw1 + l * 4096, cb1 + l * 64, cw2 + l * 4096, cw3 + l * 4096,
        cb3 + l * 64, degw, a_bf, cc_buf);
    agg_kernel<<<agg_blocks, 256, 0, stream>>>(
        a_bf, (const float4*)cc_buf, row_off, csr, (float4*)h);
  }

  head_kernel<<<(N_GRAPHS * 64 + 255) / 256, 256, 0, stream>>>(
      h, batch, l1w, l1b, l2w, l2b, out);
}